// Round 23
// baseline (78.458 us; speedup 1.0000x reference)
//
#include <hip/hip_runtime.h>

typedef _Float16 half4 __attribute__((ext_vector_type(4)));
typedef float f32x4 __attribute__((ext_vector_type(4)));
typedef float f32x2 __attribute__((ext_vector_type(2)));

// prep:
//  w1s=256*w1, b1s=256*b1, b2s=256*b2, b1fs=256*fc1_b (exact binade shifts)
//  wsB: conv2 B-frags fp16-split [ntile2][tap9][split2][lane64][j4]
//  wsF: fc1  B-frags fp16-split [chunk98][split2][ntile8][lane64][j4]
__global__ void prep_kernel(const float* __restrict__ w1, const float* __restrict__ b1,
                            const float* __restrict__ w2, const float* __restrict__ b2,
                            const float* __restrict__ f1w, const float* __restrict__ f1b,
                            _Float16* __restrict__ wsB, _Float16* __restrict__ wsF,
                            float* __restrict__ w1s, float* __restrict__ b1s,
                            float* __restrict__ b2s, float* __restrict__ b1fs) {
    int i = blockIdx.x * 256 + threadIdx.x;
    if (i < 144) w1s[i]  = __fmul_rn(w1[i], 256.0f);
    if (i < 16)  b1s[i]  = __fmul_rn(b1[i], 256.0f);
    if (i < 32)  b2s[i]  = __fmul_rn(b2[i], 256.0f);
    if (i < 128) b1fs[i] = __fmul_rn(f1b[i], 256.0f);
    if (i < 9216) {
        int ntile = i / 4608, r = i - ntile * 4608;
        int tap = r / 512;  int r2 = r - tap * 512;
        int split = r2 / 256; int lidx = r2 - split * 256;
        int lane = lidx >> 2, j = lidx & 3;
        int ic = ((lane >> 4) << 2) + j;
        int oc = ntile * 16 + (lane & 15);
        float w = w2[oc * 144 + ic * 9 + tap];
        _Float16 wh = (_Float16)w;
        wsB[i] = split ? (_Float16)(w - (float)wh) : wh;
    }
    if (i < 401408) {
        int c = i / 4096, rem = i - c * 4096;
        int sp = rem / 2048; int r2 = rem - sp * 2048;
        int nt = r2 / 256; int lidx = r2 - nt * 256;
        int lane = lidx >> 2, j = lidx & 3;
        int k = c * 16 + ((lane >> 4) << 2) + j;
        int o = nt * 16 + (lane & 15);
        float w = f1w[(size_t)o * 1568 + k];
        _Float16 wh = (_Float16)w;
        wsF[i] = sp ? (_Float16)(w - (float)wh) : wh;
    }
}

// conv: 2 samples / 512 threads (8 waves) — halves per-CU block-slots & barriers;
// occupancy stays at the 32-wave cap (4 blocks x 8 waves; LDS 31.2 KB).
// Per-sample math bit-identical to R22 (pk-FMA conv1, dual split-acc MFMA conv2,
// pooled monotone-commute epilogues, setprio around MFMA).
#define ICGS 1168

__global__ __launch_bounds__(512, 8) void conv_kernel(
    const float* __restrict__ x,
    const float* __restrict__ w1s, const float* __restrict__ b1s,
    const _Float16* __restrict__ wsB, const float* __restrict__ b2s,
    _Float16* __restrict__ h2h)
{
    __shared__ __align__(16) union {
        float xs[2][900];          // conv1 inputs (phase 1)
        short c2h[2][3136];        // h-pooled conv2 q-codes (phase 2; fully written)
    } u;
    __shared__ __align__(16) _Float16 h1h[2][4 * ICGS];  // [smp][icg4][row16][col18][4ic]

    const int t = threadIdx.x;
    const int s0 = blockIdx.x * 2;
    const int lane = t & 63;
    const int wid = t >> 6;        // 0..7

    // compact border zero-init (read-but-never-written entries only), x2 samples
    if (t < 480) {
        int sm = t / 240, r0 = t - sm * 240;
        int icg = r0 / 60, r = r0 - icg * 60;
        int row, col;
        if (r < 16)      { row = 0;      col = r; }
        else if (r < 32) { row = 15;     col = r - 16; }
        else if (r < 46) { row = r - 31; col = 0; }
        else             { row = r - 45; col = 15; }
        *(int2*)&h1h[sm][icg * ICGS + (row * 18 + col) * 4] = make_int2(0, 0);
    }
    {
        int tt = t - 480 + 232;    // reuse tail threads? keep simple: separate check
    }
    if (t < 232) {
        int sm = t / 116, r = t - sm * 116;
        int idx;
        if (r < 30)      idx = r;
        else if (r < 60) idx = 29 * 30 + (r - 30);
        else if (r < 88) idx = (r - 60 + 1) * 30;
        else             idx = (r - 88 + 1) * 30 + 29;
        u.xs[sm][idx] = 0.0f;
    }
    __syncthreads();

    for (int i = t; i < 1568; i += 512) {
        int sm = (i >= 784) ? 1 : 0;
        int j = i - 784 * sm;
        int r = j / 28, c = j - r * 28;
        u.xs[sm][(r + 1) * 30 + c + 1] = x[(size_t)(s0 + sm) * 784 + j];
    }
    __syncthreads();

    // ---- conv1 (x256 weights) + pool1 + fpq + relu -> h1h fp16 q-codes ----
    {
        const int tq = (t < 392) ? t : 391;
        const int sm = (tq >= 196) ? 1 : 0;
        const int p  = tq - 196 * sm;
        const int py = p / 14, px = p - 14 * (p / 14);
        const int r0 = 2 * py, c0 = 2 * px;
        float patch[16];
        #pragma unroll
        for (int i = 0; i < 4; ++i)
            #pragma unroll
            for (int j = 0; j < 4; ++j)
                patch[i * 4 + j] = u.xs[sm][(r0 + i) * 30 + c0 + j];
        #pragma unroll 2
        for (int oc = 0; oc < 16; ++oc) {
            f32x2 a01 = {0.f, 0.f}, a23 = {0.f, 0.f};   // -> v_pk_fma_f32
            #pragma unroll
            for (int ky = 0; ky < 3; ++ky)
                #pragma unroll
                for (int kx = 0; kx < 3; ++kx) {
                    float w = w1s[oc * 9 + ky * 3 + kx];   // uniform s_load
                    f32x2 wv = {w, w};
                    f32x2 p01 = {patch[ky * 4 + kx],       patch[ky * 4 + kx + 1]};
                    f32x2 p23 = {patch[(ky + 1) * 4 + kx], patch[(ky + 1) * 4 + kx + 1]};
                    a01 = __builtin_elementwise_fma(p01, wv, a01);
                    a23 = __builtin_elementwise_fma(p23, wv, a23);
                }
            // pool-then-quantize (monotone-commute, bit-identical)
            f32x2 mm = __builtin_elementwise_max(a01, a23);
            float m = fmaxf(mm.x, mm.y);
            float q = fmaxf(rintf(__fadd_rn(m, b1s[oc])), 0.f);
            if (t < 392)
                h1h[sm][(oc >> 2) * ICGS + ((py + 1) * 18 + (px + 1)) * 4 + (oc & 3)] = (_Float16)q;
        }
    }
    __syncthreads();   // h1h ready; xs dead -> c2h reuse

    // ---- conv2 MFMA: 52 (sm,nt,mt) tasks, round-robin over 8 waves ----
    const half4* __restrict__ wsB4 = (const half4*)wsB;
    {
        half4 bh[9], bl[9];
        int cur_nt = -1;
        for (int task = wid; task < 52; task += 8) {
            const int sm = task / 26;
            const int r26 = task - sm * 26;
            const int nt = r26 / 13;
            const int mt = r26 - nt * 13;
            if (nt != cur_nt) {
                cur_nt = nt;
                #pragma unroll
                for (int tap = 0; tap < 9; ++tap) {
                    bh[tap] = wsB4[(size_t)((nt * 9 + tap) * 2 + 0) * 64 + lane];
                    bl[tap] = wsB4[(size_t)((nt * 9 + tap) * 2 + 1) * 64 + lane];
                }
            }
            const float bb = b2s[nt * 16 + (lane & 15)];
            int p = mt * 16 + (lane & 15);
            p = (p < 196) ? p : 195;
            const int y = p / 14, xx = p - 14 * (p / 14);
            const _Float16* abase = h1h[sm] + (lane >> 4) * ICGS + (y * 18 + xx) * 4;

            f32x4 acch = {0.f, 0.f, 0.f, 0.f};
            f32x4 accl = {0.f, 0.f, 0.f, 0.f};
            __builtin_amdgcn_s_setprio(1);
            #pragma unroll
            for (int tap = 0; tap < 9; ++tap) {
                const int aoff = ((tap / 3) * 18 + (tap % 3)) * 4;
                half4 a = *(const half4*)(abase + aoff);
                acch = __builtin_amdgcn_mfma_f32_16x16x16f16(a, bh[tap], acch, 0, 0, 0);
                accl = __builtin_amdgcn_mfma_f32_16x16x16f16(a, bl[tap], accl, 0, 0, 0);
            }
            __builtin_amdgcn_s_setprio(0);
            const int oc = nt * 16 + (lane & 15);
            const int pix0 = mt * 16 + (lane >> 4) * 4;     // multiple of 4
            if (pix0 < 196) {
                float x0 = __fadd_rn(acch[0], accl[0]);
                float x1 = __fadd_rn(acch[1], accl[1]);
                float x2 = __fadd_rn(acch[2], accl[2]);
                float x3 = __fadd_rn(acch[3], accl[3]);
                float h01 = fmaxf(rintf(__fadd_rn(fmaxf(x0, x1), bb)), 0.f);
                float h23 = fmaxf(rintf(__fadd_rn(fmaxf(x2, x3), bb)), 0.f);
                int p2 = pix0 + 2;
                u.c2h[sm][oc * 98 + (pix0 / 14) * 7 + ((pix0 % 14) >> 1)] = (short)(int)h01;
                u.c2h[sm][oc * 98 + (p2   / 14) * 7 + ((p2   % 14) >> 1)] = (short)(int)h23;
            }
        }
    }
    __syncthreads();

    // ---- vertical pool -> h2h fp16 q-codes ([oc][7][7] order; exact) ----
    for (int i = t; i < 3136; i += 512) {
        int sm = (i >= 1568) ? 1 : 0;
        int j = i - 1568 * sm;
        int oc = j / 49, q = j - oc * 49;
        int qy = q / 7, qx = q - 7 * (q / 7);
        int m = max((int)u.c2h[sm][oc * 98 + (2 * qy) * 7 + qx],
                    (int)u.c2h[sm][oc * 98 + (2 * qy + 1) * 7 + qx]);
        h2h[(size_t)(s0 + sm) * 1568 + j] = (_Float16)(float)m;
    }
}

// fc (R22-proven K-split): 16 samples/block, 1024 threads = 16 waves (nt x kh).
__global__ __launch_bounds__(1024) void fc_kernel(
    const _Float16* __restrict__ h2h,
    const _Float16* __restrict__ wsF, const float* __restrict__ b1fs,
    const float* __restrict__ w2f, const float* __restrict__ b2f,
    float* __restrict__ out)
{
    __shared__ __align__(16) _Float16 Ash[16 * 394 * 4];
    __shared__ __align__(16) float Fp[8 * 64 * 4];
    __shared__ short Fsm[16 * 132];

    const int t = threadIdx.x;
    const int s0 = blockIdx.x * 16;
    const int lane = t & 63;
    const int w  = t >> 6;
    const int nt = w & 7;
    const int kh = w >> 3;

    for (int i = t; i < 3136; i += 1024) {
        int r = i / 196, c = i - r * 196;
        ((int4*)Ash)[r * 197 + c] = *(const int4*)(h2h + (size_t)(s0 + r) * 1568 + c * 8);
    }
    __syncthreads();

    const half4* __restrict__ wsF4 = (const half4*)wsF;
    const half4* __restrict__ Ash4 = (const half4*)Ash;
    f32x4 acch = {0.f, 0.f, 0.f, 0.f};
    f32x4 accl = {0.f, 0.f, 0.f, 0.f};

    const int cbeg = kh * 49;
    __builtin_amdgcn_s_setprio(1);
    for (int c = cbeg; c < cbeg + 49; ++c) {
        const int kg = c * 4 + (lane >> 4);
        half4 a = Ash4[(lane & 15) * 394 + kg];
        const size_t base = (size_t)(c * 2) * 512 + (size_t)nt * 64 + lane;
        half4 bh = wsF4[base];
        half4 bl = wsF4[base + 512];
        acch = __builtin_amdgcn_mfma_f32_16x16x16f16(a, bh, acch, 0, 0, 0);
        accl = __builtin_amdgcn_mfma_f32_16x16x16f16(a, bl, accl, 0, 0, 0);
    }
    __builtin_amdgcn_s_setprio(0);

    float acc[4];
    #pragma unroll
    for (int j = 0; j < 4; ++j) acc[j] = __fadd_rn(acch[j], accl[j]);

    if (kh == 1) {
        #pragma unroll
        for (int j = 0; j < 4; ++j) Fp[(nt * 64 + lane) * 4 + j] = acc[j];
    }
    __syncthreads();
    if (kh == 0) {
        const float bb = b1fs[nt * 16 + (lane & 15)];
        const int rbase = (lane >> 4) * 4;
        #pragma unroll
        for (int j = 0; j < 4; ++j) {
            float tot = __fadd_rn(acc[j], Fp[(nt * 64 + lane) * 4 + j]);
            float qv = fmaxf(rintf(__fadd_rn(tot, bb)), 0.f);
            Fsm[(rbase + j) * 132 + nt * 16 + (lane & 15)] = (short)(int)qv;
        }
    }
    __syncthreads();

    if (t < 160) {
        int r = t / 10, c = t - 10 * (t / 10);
        const float* wr = w2f + c * 128;
        double a2 = 0.0;
        #pragma unroll 8
        for (int k = 0; k < 128; ++k)
            a2 = fma((double)Fsm[r * 132 + k], (double)wr[k], a2);
        out[(size_t)(s0 + r) * 10 + c] = (float)(a2 * 0.00390625 + (double)b2f[c]);
    }
}

extern "C" void kernel_launch(void* const* d_in, const int* in_sizes, int n_in,
                              void* d_out, int out_size, void* d_ws, size_t ws_size,
                              hipStream_t stream) {
    const float* x   = (const float*)d_in[0];
    const float* c1w = (const float*)d_in[1];
    const float* c1b = (const float*)d_in[2];
    const float* c2w = (const float*)d_in[3];
    const float* c2b = (const float*)d_in[4];
    const float* f1w = (const float*)d_in[5];
    const float* f1b = (const float*)d_in[6];
    const float* f2w = (const float*)d_in[7];
    const float* f2b = (const float*)d_in[8];
    float* out = (float*)d_out;

    const int B = in_sizes[0] / 784;              // 4096

    _Float16* wsB = (_Float16*)d_ws;              // [9216]
    _Float16* wsF = wsB + 9216;                   // [401408]
    float* fbase  = (float*)(wsF + 401408);
    float* w1s  = fbase;                          // [144]
    float* b1s  = w1s + 144;                      // [16]
    float* b2s  = b1s + 16;                       // [32]
    float* b1fs = b2s + 32;                       // [128]
    _Float16* h2h = (_Float16*)(b1fs + 128);      // [B][1568] fp16 q-codes

    prep_kernel<<<1568, 256, 0, stream>>>(c1w, c1b, c2w, c2b, f1w, f1b,
                                          wsB, wsF, w1s, b1s, b2s, b1fs);
    conv_kernel<<<B / 2, 512, 0, stream>>>(x, w1s, b1s, wsB, b2s, h2h);
    fc_kernel<<<B / 16, 1024, 0, stream>>>(h2h, wsF, b1fs, f2w, f2b, out);
}

// Round 24
// 69.240 us; speedup vs baseline: 1.1331x; 1.1331x over previous
//
#include <hip/hip_runtime.h>

typedef _Float16 half4 __attribute__((ext_vector_type(4)));
typedef float f32x4 __attribute__((ext_vector_type(4)));
typedef float f32x2 __attribute__((ext_vector_type(2)));

// prep:
//  w1s=256*w1, b1s=256*b1, b2s=256*b2, b1fs=256*fc1_b (exact binade shifts)
//  wsB: conv2 B-frags fp16-split [ntile2][tap9][split2][lane64][j4]
//  wsF: fc1  B-frags fp16-split [chunk98][split2][ntile8][lane64][j4]
__global__ void prep_kernel(const float* __restrict__ w1, const float* __restrict__ b1,
                            const float* __restrict__ w2, const float* __restrict__ b2,
                            const float* __restrict__ f1w, const float* __restrict__ f1b,
                            _Float16* __restrict__ wsB, _Float16* __restrict__ wsF,
                            float* __restrict__ w1s, float* __restrict__ b1s,
                            float* __restrict__ b2s, float* __restrict__ b1fs) {
    int i = blockIdx.x * 256 + threadIdx.x;
    if (i < 144) w1s[i]  = __fmul_rn(w1[i], 256.0f);
    if (i < 16)  b1s[i]  = __fmul_rn(b1[i], 256.0f);
    if (i < 32)  b2s[i]  = __fmul_rn(b2[i], 256.0f);
    if (i < 128) b1fs[i] = __fmul_rn(f1b[i], 256.0f);
    if (i < 9216) {
        int ntile = i / 4608, r = i - ntile * 4608;
        int tap = r / 512;  int r2 = r - tap * 512;
        int split = r2 / 256; int lidx = r2 - split * 256;
        int lane = lidx >> 2, j = lidx & 3;
        int ic = ((lane >> 4) << 2) + j;
        int oc = ntile * 16 + (lane & 15);
        float w = w2[oc * 144 + ic * 9 + tap];
        _Float16 wh = (_Float16)w;
        wsB[i] = split ? (_Float16)(w - (float)wh) : wh;
    }
    if (i < 401408) {
        int c = i / 4096, rem = i - c * 4096;
        int sp = rem / 2048; int r2 = rem - sp * 2048;
        int nt = r2 / 256; int lidx = r2 - nt * 256;
        int lane = lidx >> 2, j = lidx & 3;
        int k = c * 16 + ((lane >> 4) << 2) + j;
        int o = nt * 16 + (lane & 15);
        float w = f1w[(size_t)o * 1568 + k];
        _Float16 wh = (_Float16)w;
        wsF[i] = sp ? (_Float16)(w - (float)wh) : wh;
    }
}

// conv (R22-proven): conv1 VALU (pk pairs; pool-then-quantize) -> conv2 K=16 MFMA
// (dual split-acc, nt-major round-robin, setprio around MFMA cluster) -> v-pool.
#define ICGS 1168

__global__ __launch_bounds__(256, 8) void conv_kernel(
    const float* __restrict__ x,
    const float* __restrict__ w1s, const float* __restrict__ b1s,
    const _Float16* __restrict__ wsB, const float* __restrict__ b2s,
    _Float16* __restrict__ h2h)
{
    __shared__ __align__(16) union {
        float xs[900];            // conv1 input (phase 1)
        short c2h[32 * 98];       // h-pooled conv2 q-codes (phase 2; fully written)
    } u;
    __shared__ __align__(16) _Float16 h1h[4 * ICGS];  // [icg4][row16][col18][4ic]

    const int t = threadIdx.x;
    const int s = blockIdx.x;
    const int lane = t & 63;
    const int wid = t >> 6;

    // compact border zero-init (read-but-never-written entries only)
    if (t < 240) {
        int icg = t / 60, r = t - icg * 60;
        int row, col;
        if (r < 16)      { row = 0;      col = r; }
        else if (r < 32) { row = 15;     col = r - 16; }
        else if (r < 46) { row = r - 31; col = 0; }
        else             { row = r - 45; col = 15; }
        *(int2*)&h1h[icg * ICGS + (row * 18 + col) * 4] = make_int2(0, 0);
    }
    if (t < 116) {
        int idx;
        if (t < 30)      idx = t;
        else if (t < 60) idx = 29 * 30 + (t - 30);
        else if (t < 88) idx = (t - 60 + 1) * 30;
        else             idx = (t - 88 + 1) * 30 + 29;
        u.xs[idx] = 0.0f;
    }
    __syncthreads();

    const float* xin = x + (size_t)s * 784;
    for (int i = t; i < 784; i += 256) {
        int r = i / 28, c = i - r * 28;
        u.xs[(r + 1) * 30 + c + 1] = xin[i];
    }
    __syncthreads();

    // ---- conv1 (x256 weights) + pool1 + fpq + relu -> h1h fp16 q-codes ----
    {
        const int p  = (t < 196) ? t : 195;
        const int py = p / 14, px = p - 14 * (p / 14);
        const int r0 = 2 * py, c0 = 2 * px;
        float patch[16];
        #pragma unroll
        for (int i = 0; i < 4; ++i)
            #pragma unroll
            for (int j = 0; j < 4; ++j)
                patch[i * 4 + j] = u.xs[(r0 + i) * 30 + c0 + j];
        #pragma unroll 2
        for (int oc = 0; oc < 16; ++oc) {
            f32x2 a01 = {0.f, 0.f}, a23 = {0.f, 0.f};   // -> v_pk_fma_f32
            #pragma unroll
            for (int ky = 0; ky < 3; ++ky)
                #pragma unroll
                for (int kx = 0; kx < 3; ++kx) {
                    float w = w1s[oc * 9 + ky * 3 + kx];   // uniform s_load
                    f32x2 wv = {w, w};
                    f32x2 p01 = {patch[ky * 4 + kx],       patch[ky * 4 + kx + 1]};
                    f32x2 p23 = {patch[(ky + 1) * 4 + kx], patch[(ky + 1) * 4 + kx + 1]};
                    a01 = __builtin_elementwise_fma(p01, wv, a01);
                    a23 = __builtin_elementwise_fma(p23, wv, a23);
                }
            // pool-then-quantize (monotone-commute, bit-identical)
            f32x2 mm = __builtin_elementwise_max(a01, a23);
            float m = fmaxf(mm.x, mm.y);
            float q = fmaxf(rintf(__fadd_rn(m, b1s[oc])), 0.f);
            if (t < 196)
                h1h[(oc >> 2) * ICGS + ((py + 1) * 18 + (px + 1)) * 4 + (oc & 3)] = (_Float16)q;
        }
    }
    __syncthreads();   // h1h ready; xs dead -> c2h reuse

    // ---- conv2 MFMA: 26 (nt,mt) tasks nt-major, round-robin over 4 waves ----
    const half4* __restrict__ wsB4 = (const half4*)wsB;
    {
        half4 bh[9], bl[9];
        int cur_nt = -1;
        for (int task = wid; task < 26; task += 4) {
            const int nt = task / 13;
            const int mt = task - nt * 13;
            if (nt != cur_nt) {            // <=2 B-frag (re)loads per wave
                cur_nt = nt;
                #pragma unroll
                for (int tap = 0; tap < 9; ++tap) {
                    bh[tap] = wsB4[(size_t)((nt * 9 + tap) * 2 + 0) * 64 + lane];
                    bl[tap] = wsB4[(size_t)((nt * 9 + tap) * 2 + 1) * 64 + lane];
                }
            }
            const float bb = b2s[nt * 16 + (lane & 15)];
            int p = mt * 16 + (lane & 15);
            p = (p < 196) ? p : 195;
            const int y = p / 14, xx = p - 14 * (p / 14);
            const _Float16* abase = h1h + (lane >> 4) * ICGS + (y * 18 + xx) * 4;

            f32x4 acch = {0.f, 0.f, 0.f, 0.f};
            f32x4 accl = {0.f, 0.f, 0.f, 0.f};
            __builtin_amdgcn_s_setprio(1);
            #pragma unroll
            for (int tap = 0; tap < 9; ++tap) {
                const int aoff = ((tap / 3) * 18 + (tap % 3)) * 4;
                half4 a = *(const half4*)(abase + aoff);
                acch = __builtin_amdgcn_mfma_f32_16x16x16f16(a, bh[tap], acch, 0, 0, 0);
                accl = __builtin_amdgcn_mfma_f32_16x16x16f16(a, bl[tap], accl, 0, 0, 0);
            }
            __builtin_amdgcn_s_setprio(0);
            const int oc = nt * 16 + (lane & 15);
            const int pix0 = mt * 16 + (lane >> 4) * 4;     // multiple of 4
            if (pix0 < 196) {
                float x0 = __fadd_rn(acch[0], accl[0]);
                float x1 = __fadd_rn(acch[1], accl[1]);
                float x2 = __fadd_rn(acch[2], accl[2]);
                float x3 = __fadd_rn(acch[3], accl[3]);
                float h01 = fmaxf(rintf(__fadd_rn(fmaxf(x0, x1), bb)), 0.f);
                float h23 = fmaxf(rintf(__fadd_rn(fmaxf(x2, x3), bb)), 0.f);
                int p2 = pix0 + 2;
                u.c2h[oc * 98 + (pix0 / 14) * 7 + ((pix0 % 14) >> 1)] = (short)(int)h01;
                u.c2h[oc * 98 + (p2   / 14) * 7 + ((p2   % 14) >> 1)] = (short)(int)h23;
            }
        }
    }
    __syncthreads();

    // ---- vertical pool -> h2h fp16 q-codes ([oc][7][7] order; exact) ----
    _Float16* h2o = h2h + (size_t)s * 1568;
    for (int i = t; i < 1568; i += 256) {
        int oc = i / 49, q = i - oc * 49;
        int qy = q / 7, qx = q - 7 * (q / 7);
        int m = max((int)u.c2h[oc * 98 + (2 * qy) * 7 + qx],
                    (int)u.c2h[oc * 98 + (2 * qy + 1) * 7 + qx]);
        h2o[i] = (_Float16)(float)m;
    }
}

// fc (K-split, R22-proven): 16 samples/block, 1024 threads = 16 waves (nt x kh).
// kh=1 deposits f32 partials in LDS; kh=0 combines ((h0+l0)+(h1+l1))+bias,
// fpq, relu -> Fsm. fc2: f64 raw pre-quant output (validated hedge).
__global__ __launch_bounds__(1024) void fc_kernel(
    const _Float16* __restrict__ h2h,
    const _Float16* __restrict__ wsF, const float* __restrict__ b1fs,
    const float* __restrict__ w2f, const float* __restrict__ b2f,
    float* __restrict__ out)
{
    __shared__ __align__(16) _Float16 Ash[16 * 394 * 4]; // [sample][kg 392+pad][4]
    __shared__ __align__(16) float Fp[8 * 64 * 4];       // kh=1 partials [nt][lane][4]
    __shared__ short Fsm[16 * 132];

    const int t = threadIdx.x;
    const int s0 = blockIdx.x * 16;
    const int lane = t & 63;
    const int w  = t >> 6;          // 0..15
    const int nt = w & 7;
    const int kh = w >> 3;

    for (int i = t; i < 3136; i += 1024) {
        int r = i / 196, c = i - r * 196;
        ((int4*)Ash)[r * 197 + c] = *(const int4*)(h2h + (size_t)(s0 + r) * 1568 + c * 8);
    }
    __syncthreads();

    const half4* __restrict__ wsF4 = (const half4*)wsF;
    const half4* __restrict__ Ash4 = (const half4*)Ash;
    f32x4 acch = {0.f, 0.f, 0.f, 0.f};
    f32x4 accl = {0.f, 0.f, 0.f, 0.f};

    const int cbeg = kh * 49;
    __builtin_amdgcn_s_setprio(1);
    for (int c = cbeg; c < cbeg + 49; ++c) {
        const int kg = c * 4 + (lane >> 4);
        half4 a = Ash4[(lane & 15) * 394 + kg];
        const size_t base = (size_t)(c * 2) * 512 + (size_t)nt * 64 + lane;
        half4 bh = wsF4[base];
        half4 bl = wsF4[base + 512];
        acch = __builtin_amdgcn_mfma_f32_16x16x16f16(a, bh, acch, 0, 0, 0);
        accl = __builtin_amdgcn_mfma_f32_16x16x16f16(a, bl, accl, 0, 0, 0);
    }
    __builtin_amdgcn_s_setprio(0);

    float acc[4];
    #pragma unroll
    for (int j = 0; j < 4; ++j) acc[j] = __fadd_rn(acch[j], accl[j]);

    if (kh == 1) {
        #pragma unroll
        for (int j = 0; j < 4; ++j) Fp[(nt * 64 + lane) * 4 + j] = acc[j];
    }
    __syncthreads();
    if (kh == 0) {
        const float bb = b1fs[nt * 16 + (lane & 15)];
        const int rbase = (lane >> 4) * 4;
        #pragma unroll
        for (int j = 0; j < 4; ++j) {
            float tot = __fadd_rn(acc[j], Fp[(nt * 64 + lane) * 4 + j]);
            float qv = fmaxf(rintf(__fadd_rn(tot, bb)), 0.f);
            Fsm[(rbase + j) * 132 + nt * 16 + (lane & 15)] = (short)(int)qv;
        }
    }
    __syncthreads();

    if (t < 160) {
        int r = t / 10, c = t - 10 * (t / 10);
        const float* wr = w2f + c * 128;
        double a2 = 0.0;
        #pragma unroll 8
        for (int k = 0; k < 128; ++k)
            a2 = fma((double)Fsm[r * 132 + k], (double)wr[k], a2);
        out[(size_t)(s0 + r) * 10 + c] = (float)(a2 * 0.00390625 + (double)b2f[c]);
    }
}

extern "C" void kernel_launch(void* const* d_in, const int* in_sizes, int n_in,
                              void* d_out, int out_size, void* d_ws, size_t ws_size,
                              hipStream_t stream) {
    const float* x   = (const float*)d_in[0];
    const float* c1w = (const float*)d_in[1];
    const float* c1b = (const float*)d_in[2];
    const float* c2w = (const float*)d_in[3];
    const float* c2b = (const float*)d_in[4];
    const float* f1w = (const float*)d_in[5];
    const float* f1b = (const float*)d_in[6];
    const float* f2w = (const float*)d_in[7];
    const float* f2b = (const float*)d_in[8];
    float* out = (float*)d_out;

    const int B = in_sizes[0] / 784;              // 4096

    _Float16* wsB = (_Float16*)d_ws;              // [9216]
    _Float16* wsF = wsB + 9216;                   // [401408]
    float* fbase  = (float*)(wsF + 401408);
    float* w1s  = fbase;                          // [144]
    float* b1s  = w1s + 144;                      // [16]
    float* b2s  = b1s + 16;                       // [32]
    float* b1fs = b2s + 32;                       // [128]
    _Float16* h2h = (_Float16*)(b1fs + 128);      // [B][1568] fp16 q-codes

    prep_kernel<<<1568, 256, 0, stream>>>(c1w, c1b, c2w, c2b, f1w, f1b,
                                          wsB, wsF, w1s, b1s, b2s, b1fs);
    conv_kernel<<<B, 256, 0, stream>>>(x, w1s, b1s, wsB, b2s, h2h);
    fc_kernel<<<B / 16, 1024, 0, stream>>>(h2h, wsF, b1fs, f2w, f2b, out);
}